// Round 6
// baseline (336.762 us; speedup 1.0000x reference)
//
#include <hip/hip_runtime.h>
#include <hip/hip_bf16.h>
#include <math.h>

// TreeLSTM, B=8, L=4096, D=300, H=128, 12 levels. Round 12:
// - R11 post-mortem: __launch_bounds__(512,4) capped VGPR at 64 -> Wfr[5][8]
//   (160 VGPRs) spilled to scratch: FETCH/WRITE 135/138 MB of spill traffic.
//   Weight-stationary REQUIRES <=2 waves/SIMD (256-VGPR budget).
// - fused2 rebuilt in the proven level_ws register shape: 256 thr / 4 waves,
//   (256,2); each wave handles 2 h-groups SEQUENTIALLY (#pragma unroll 1 ->
//   one Wfr set live). 64 L-rows/block, LDS 80 KB = 2 blocks/CU, L12 grid =
//   256 = all CUs. Levels 1..8 = 4 fused pairs; 9..12 = single-block finish.
// - reorder dispatch eliminated: WcatC written by 160 leaf blocks (consumers
//   are later dispatches); leaf stages B by on-the-fly W_leaf fp32->bf16
//   conversion into LDS (WlfC removed). 6 dispatches total.

typedef __attribute__((ext_vector_type(8))) short bfrag8;   // 8 bf16 = 4 VGPRs
typedef __attribute__((ext_vector_type(4))) float f32x4;

__device__ __forceinline__ float rcpf(float x) { return __builtin_amdgcn_rcpf(x); }
__device__ __forceinline__ float sigf(float x) { return rcpf(1.0f + __expf(-x)); }
__device__ __forceinline__ float tanh_f(float x) {
    float e = __expf(2.0f * x);              // x>>0: e=inf -> rcp=0 -> 1 ; x<<0: e=0 -> -1
    return 1.0f - 2.0f * rcpf(e + 1.0f);
}
__device__ __forceinline__ short f2bf(float f) {
    __hip_bfloat16 h = __float2bfloat16(f);
    return *reinterpret_cast<short*>(&h);
}
__device__ __forceinline__ bfrag8 pack8(f32x4 a, f32x4 b) {
    union { int i[4]; bfrag8 v; } u;
    asm("v_cvt_pk_bf16_f32 %0, %1, %2" : "=v"(u.i[0]) : "v"(a[0]), "v"(a[1]));
    asm("v_cvt_pk_bf16_f32 %0, %1, %2" : "=v"(u.i[1]) : "v"(a[2]), "v"(a[3]));
    asm("v_cvt_pk_bf16_f32 %0, %1, %2" : "=v"(u.i[2]) : "v"(b[0]), "v"(b[1]));
    asm("v_cvt_pk_bf16_f32 %0, %1, %2" : "=v"(u.i[3]) : "v"(b[2]), "v"(b[3]));
    return u.v;
}
#define GLDS(gp, lp) __builtin_amdgcn_global_load_lds( \
    (const __attribute__((address_space(1))) void*)(gp), \
    (__attribute__((address_space(3))) void*)(lp), 16, 0, 0)

// ---------------- leaf: [32768,320fp32]@[320,256] + bias, split h/c ----------------
// Fused x fp32->bf16 convert (swizzled GLDS source + cvt_pk), on-the-fly
// W_leaf fp32->bf16 B staging, and WcatC reorder folded into blocks
// (y==0, x<160) -- consumed only by later dispatches, no sync needed.
__global__ __launch_bounds__(256) void leaf_kernel(
    const float* __restrict__ x,     const float* __restrict__ Wleaf,
    const float* __restrict__ W_l,   const float* __restrict__ W_r,
    const float* __restrict__ bleaf,
    short* __restrict__ hD,       // level-1 A, chunk layout [32][16384] units
    float* __restrict__ cD,       // [32768][128] fp32
    short* __restrict__ Wcat_ch)  // [32][640] chunk units (for later levels)
{
    __shared__ float Als[128 * 64];     // 32 KB: [row][16 units of 4 floats], swizzled
    __shared__ short Bls[8 * 128 * 8];  // 16 KB: [c][n] units
    const int tid  = threadIdx.x;
    const int w    = tid >> 6, lane = tid & 63;
    const int quad = lane >> 4, l16 = lane & 15;
    const int mBlk = blockIdx.x * 128, nBlk = blockIdx.y * 128;
    const int waveM = (w >> 1) * 64, waveN = (w & 1) * 64;

    // ---- folded reorder: WcatC (163840 elems over 160 blocks x 1024) ----
    if (blockIdx.y == 0 && blockIdx.x < 160) {
        #pragma unroll
        for (int e = 0; e < 4; ++e) {
            int idx = blockIdx.x * 1024 + e * 256 + tid;
            int n = idx >> 8, k = idx & 255;
            float v = (k < 128) ? W_l[k * 640 + n] : W_r[(k - 128) * 640 + n];
            Wcat_ch[(((size_t)(k >> 3)) * 640 + n) * 8 + (k & 7)] = f2bf(v);
        }
    }

    f32x4 acc[4][4] = {};
    const f32x4 zero4 = {0.f, 0.f, 0.f, 0.f};

    for (int c = 0; c < 5; ++c) {           // K = 5 * 64 = 320 (300 + zero pad)
        const int k0c = c * 64;
        // ---- stage A (x) as fp32, XOR-swizzled source, linear LDS ----
        {
            const int q_lds = lane & 15;
            const int rsub  = lane >> 4;
            #pragma unroll
            for (int g = 0; g < 8; ++g) {
                int row = w * 32 + g * 4 + rsub;
                int q_g = (q_lds & 8) | ((q_lds & 7) ^ (row & 7));
                if (c < 4 || q_g < 11) {
                    GLDS(x + (size_t)(mBlk + row) * 300 + k0c + q_g * 4,
                         (char*)Als + (w * 32 + g * 4) * 256);
                } else {
                    *(f32x4*)((char*)Als + row * 256 + q_lds * 16) = zero4;  // pad k=300..319
                }
            }
        }
        // ---- stage B on the fly from W_leaf fp32 (1024 units, 4/thread) ----
        #pragma unroll
        for (int uu = 0; uu < 4; ++uu) {
            int id  = uu * 256 + tid;
            int ccl = id >> 7, nl = id & 127;   // chunk-in-iter [0,8), col [0,128)
            int k0  = (c * 8 + ccl) * 8;
            int n   = nBlk + nl;
            f32x4 v0, v1;
            #pragma unroll
            for (int jj = 0; jj < 4; ++jj)
                v0[jj] = (k0 + jj < 300) ? Wleaf[(size_t)(k0 + jj) * 256 + n] : 0.0f;
            #pragma unroll
            for (int jj = 0; jj < 4; ++jj)
                v1[jj] = (k0 + 4 + jj < 300) ? Wleaf[(size_t)(k0 + 4 + jj) * 256 + n] : 0.0f;
            *(bfrag8*)(Bls + (ccl * 128 + nl) * 8) = pack8(v0, v1);
        }
        __syncthreads();
        #pragma unroll
        for (int ks = 0; ks < 2; ++ks) {
            const int ca = ks * 4 + quad;
            bfrag8 af[4], bf4[4];
            #pragma unroll
            for (int i = 0; i < 4; ++i) {
                int r  = waveM + i * 16 + l16;
                int u0 = 2 * ca, u1 = 2 * ca + 1;
                int s0 = (u0 & 8) | ((u0 & 7) ^ (r & 7));
                int s1 = (u1 & 8) | ((u1 & 7) ^ (r & 7));
                f32x4 a0 = *(const f32x4*)(Als + r * 64 + s0 * 4);
                f32x4 a1 = *(const f32x4*)(Als + r * 64 + s1 * 4);
                af[i] = pack8(a0, a1);
            }
            #pragma unroll
            for (int jn = 0; jn < 4; ++jn)
                bf4[jn] = *(const bfrag8*)(Bls + (ca * 128 + waveN + jn * 16 + l16) * 8);
            #pragma unroll
            for (int i = 0; i < 4; ++i)
                #pragma unroll
                for (int jn = 0; jn < 4; ++jn)
                    acc[i][jn] = __builtin_amdgcn_mfma_f32_16x16x32_bf16(
                                     af[i], bf4[jn], acc[i][jn], 0, 0, 0);
        }
        __syncthreads();
    }

    #pragma unroll
    for (int i = 0; i < 4; ++i) {
        int row0 = mBlk + waveM + i * 16 + quad * 4;
        #pragma unroll
        for (int jn = 0; jn < 4; ++jn) {
            int col = nBlk + waveN + jn * 16 + l16;
            float bv = bleaf[col];
            #pragma unroll
            for (int rg = 0; rg < 4; ++rg) {
                float v = acc[i][jn][rg] + bv;
                int m = row0 + rg;
                if (nBlk == 0) {
                    int hc = col;
                    hD[(((size_t)((m & 1) * 16 + (hc >> 3))) * 16384 + (m >> 1)) * 8
                       + (hc & 7)] = f2bf(v);
                } else {
                    cD[(size_t)m * 128 + (col - 128)] = v;
                }
            }
        }
    }
}

// ---------------- fused two-level kernel: levels L, L+1 ----------------
// 256 thr / 4 waves, (256,2) = proven Wfr-resident shape. Block owns 64
// level-L rows -> 32 L+1 rows. Each wave handles h-groups {w, w+4}
// sequentially (#pragma unroll 1: ONE Wfr[5][8] set live at a time).
// LDS: Als 32 KB + hL 16 KB + cL 32 KB = 80 KB -> 2 blocks/CU.
__global__ __launch_bounds__(256, 2) void fused2_kernel(
    const short* __restrict__ A,      // [32][M1] chunk units (level-L input)
    const float* __restrict__ cprev,  // [2*M1][128] fp32
    const short* __restrict__ Wch,    // [32][640] chunk units
    const float* __restrict__ bias,   // [640]
    short* __restrict__ hout,         // level-(L+1) h, chunk stride M2>>1
    float* __restrict__ cout_,        // [M2][128] fp32
    int M2)                           // L+1 output rows; M1 = 2*M2
{
    __shared__ short Als[32 * 64 * 8];   // 32 KB: [c:0..31][row:0..63]
    __shared__ short hL [64 * 128];      // 16 KB: level-L h image (swizzled)
    __shared__ float cL [64 * 128];      // 32 KB: level-L c
    const int tid  = threadIdx.x;
    const int w    = tid >> 6, lane = tid & 63;
    const int quad = lane >> 4, l16 = lane & 15;
    const int M1   = M2 * 2;
    const int Lbase = blockIdx.x * 64;   // level-L rows [Lbase, Lbase+64)

    // ---- stage A tile: 8 GLDS/wave (level_ws pattern), no guard (grid exact)
    #pragma unroll
    for (int s = 0; s < 8; ++s)
        GLDS(A + ((size_t)(s * 4 + w) * M1 + Lbase + lane) * 8,
             (char*)Als + (s * 4 + w) * 1024);
    __syncthreads();

    // ---- level L: 64 rows, two h-group passes per wave ----
    #pragma unroll 1
    for (int p = 0; p < 2; ++p) {
        const int j = w + p * 4;
        const int h = j * 16 + l16;
        bfrag8 Wfr[5][8];
        #pragma unroll
        for (int g = 0; g < 5; ++g)
            #pragma unroll
            for (int s = 0; s < 8; ++s)
                Wfr[g][s] = *(const bfrag8*)(Wch + ((size_t)(s * 4 + quad) * 640
                                                    + g * 128 + h) * 8);
        const float bi  = bias[h],       bfl = bias[128 + h], bfr_ = bias[256 + h];
        const float bo  = bias[384 + h], bg  = bias[512 + h];

        for (int rt = 0; rt < 4; ++rt) {
            f32x4 acc[5] = {};
            #pragma unroll
            for (int s = 0; s < 8; ++s) {
                bfrag8 af = *(const bfrag8*)(Als + ((s * 4 + quad) * 64
                                                    + rt * 16 + l16) * 8);
                #pragma unroll
                for (int g = 0; g < 5; ++g)
                    acc[g] = __builtin_amdgcn_mfma_f32_16x16x32_bf16(
                                 af, Wfr[g][s], acc[g], 0, 0, 0);
            }
            #pragma unroll
            for (int rg = 0; rg < 4; ++rg) {
                int mloc = rt * 16 + quad * 4 + rg;      // [0,64)
                int mG   = Lbase + mloc;                 // global level-L row
                float gi  = acc[0][rg] + bi;
                float gfl = acc[1][rg] + bfl;
                float gfr = acc[2][rg] + bfr_;
                float go  = acc[3][rg] + bo;
                float gg  = acc[4][rg] + bg;
                float cl  = cprev[(size_t)(2 * mG) * 128 + h];
                float cr  = cprev[(size_t)(2 * mG + 1) * 128 + h];
                float cn  = sigf(gfl) * cl + sigf(gfr) * cr + sigf(gi) * tanh_f(gg);
                float hn  = sigf(go) * tanh_f(cn);
                cL[mloc * 128 + h] = cn;
                int byte = (mloc * 256 + h * 2) ^ (((mloc >> 1) & 7) << 4);
                *(short*)((char*)hL + byte) = f2bf(hn);
            }
        }
    }
    __syncthreads();

    // ---- level L+1: 32 output rows from LDS, two h-group passes ----
    const int Mn2 = M2 >> 1;
    #pragma unroll 1
    for (int p = 0; p < 2; ++p) {
        const int j = w + p * 4;
        const int h = j * 16 + l16;
        bfrag8 Wfr[5][8];
        #pragma unroll
        for (int g = 0; g < 5; ++g)
            #pragma unroll
            for (int s = 0; s < 8; ++s)
                Wfr[g][s] = *(const bfrag8*)(Wch + ((size_t)(s * 4 + quad) * 640
                                                    + g * 128 + h) * 8);
        const float bi  = bias[h],       bfl = bias[128 + h], bfr_ = bias[256 + h];
        const float bo  = bias[384 + h], bg  = bias[512 + h];

        for (int rt = 0; rt < 2; ++rt) {
            f32x4 acc[5] = {};
            #pragma unroll
            for (int s = 0; s < 8; ++s) {
                int cch  = s * 4 + quad;                     // [0,32)
                int row  = 2 * (rt * 16 + l16) + (cch >> 4); // child row [0,64)
                int byte = (row * 256 + (cch & 15) * 16) ^ (((row >> 1) & 7) << 4);
                bfrag8 af = *(const bfrag8*)((const char*)hL + byte);
                #pragma unroll
                for (int g = 0; g < 5; ++g)
                    acc[g] = __builtin_amdgcn_mfma_f32_16x16x32_bf16(
                                 af, Wfr[g][s], acc[g], 0, 0, 0);
            }
            #pragma unroll
            for (int rg = 0; rg < 4; ++rg) {
                int mloc = rt * 16 + quad * 4 + rg;          // [0,32)
                int m2   = blockIdx.x * 32 + mloc;           // global L+1 row
                float gi  = acc[0][rg] + bi;
                float gfl = acc[1][rg] + bfl;
                float gfr = acc[2][rg] + bfr_;
                float go  = acc[3][rg] + bo;
                float gg  = acc[4][rg] + bg;
                float cl  = cL[(2 * mloc) * 128 + h];
                float cr  = cL[(2 * mloc + 1) * 128 + h];
                float cn  = sigf(gfl) * cl + sigf(gfr) * cr + sigf(gi) * tanh_f(gg);
                float hn  = sigf(go) * tanh_f(cn);
                hout[(((size_t)((m2 & 1) * 16 + (h >> 3))) * Mn2 + (m2 >> 1)) * 8
                     + (h & 7)] = f2bf(hn);
                cout_[(size_t)m2 * 128 + h] = cn;
            }
        }
    }
}

// ---------------- single-block finisher: levels 9..12 ----------------
__global__ __launch_bounds__(512) void finish_kernel(
    const short* __restrict__ hin,   // [32][64] units (128-row chunk layout)
    const float* __restrict__ cin,   // [128][128] f32
    const short* __restrict__ Wch, const float* __restrict__ bias,
    float* __restrict__ out)         // [8][128]
{
    __shared__ short hP[32 * 64 * 8];   // 32 KB ping
    __shared__ short hQ[32 * 32 * 8];   // 16 KB pong
    __shared__ float cA[128 * 128];     // 64 KB
    __shared__ float cB[64 * 128];      // 32 KB
    const int tid  = threadIdx.x;
    const int w    = tid >> 6, lane = tid & 63;
    const int quad = lane >> 4, l16 = lane & 15;
    const int h    = w * 16 + l16;      // wave = h-group

    #pragma unroll
    for (int g = 0; g < 4; ++g)
        GLDS(hin + ((size_t)((g * 8 + w) * 64 + lane)) * 8,
             (char*)hP + ((g * 8 + w) * 64) * 16);
    #pragma unroll
    for (int g = 0; g < 8; ++g)
        GLDS(cin + ((size_t)((g * 8 + w) * 64 + lane)) * 4,
             (char*)cA + ((g * 8 + w) * 64) * 16);

    bfrag8 Wfr[5][8];
    #pragma unroll
    for (int g = 0; g < 5; ++g)
        #pragma unroll
        for (int s = 0; s < 8; ++s)
            Wfr[g][s] = *(const bfrag8*)(Wch + ((size_t)(s * 4 + quad) * 640
                                                + g * 128 + h) * 8);
    const float bi  = bias[h],       bfl = bias[128 + h], bfr_ = bias[256 + h];
    const float bo  = bias[384 + h], bg  = bias[512 + h];

    __syncthreads();

    #pragma unroll
    for (int t = 0; t < 4; ++t) {              // levels 9..12
        const int Mo = 64 >> t;                // 64, 32, 16, 8
        const short* hsrc = (t & 1) ? hQ : hP;
        short* hdst       = (t & 1) ? hP : hQ;
        const float* cread  = (t & 1) ? cB : cA;
        float*       cwrite = (t & 1) ? cA : cB;
        const int nrt = (Mo + 15) >> 4;

        for (int rt = 0; rt < nrt; ++rt) {
            f32x4 acc[5] = {};
            #pragma unroll
            for (int s = 0; s < 8; ++s) {
                bfrag8 af = *(const bfrag8*)(hsrc + ((s * 4 + quad) * Mo
                                                     + rt * 16 + l16) * 8);
                #pragma unroll
                for (int g = 0; g < 5; ++g)
                    acc[g] = __builtin_amdgcn_mfma_f32_16x16x32_bf16(
                                 af, Wfr[g][s], acc[g], 0, 0, 0);
            }
            #pragma unroll
            for (int rg = 0; rg < 4; ++rg) {
                int m = rt * 16 + quad * 4 + rg;
                if (m < Mo) {
                    float gi  = acc[0][rg] + bi;
                    float gfl = acc[1][rg] + bfl;
                    float gfr = acc[2][rg] + bfr_;
                    float go  = acc[3][rg] + bo;
                    float gg  = acc[4][rg] + bg;
                    float cl  = cread[(2 * m) * 128 + h];
                    float cr  = cread[(2 * m + 1) * 128 + h];
                    float cn  = sigf(gfl) * cl + sigf(gfr) * cr + sigf(gi) * tanh_f(gg);
                    float hn  = sigf(go) * tanh_f(cn);
                    if (t == 3) {
                        out[(size_t)m * 128 + h] = hn;
                    } else {
                        hdst[(((m & 1) * 16 + (h >> 3)) * (Mo >> 1) + (m >> 1)) * 8
                             + (h & 7)] = f2bf(hn);
                        cwrite[m * 128 + h] = cn;
                    }
                }
            }
        }
        __syncthreads();
    }
}

extern "C" void kernel_launch(void* const* d_in, const int* in_sizes, int n_in,
                              void* d_out, int out_size, void* d_ws, size_t ws_size,
                              hipStream_t stream)
{
    const float* x      = (const float*)d_in[0];
    const float* W_leaf = (const float*)d_in[1];
    const float* b_leaf = (const float*)d_in[2];
    const float* W_l    = (const float*)d_in[3];
    const float* W_r    = (const float*)d_in[4];
    const float* b      = (const float*)d_in[5];
    float* out = (float*)d_out;

    // workspace (~38.2 MB)
    char* p = (char*)d_ws;
    short* hA    = (short*)p; p += (size_t)32 * 16384 * 16 + 1024; //  8.4 MB
    short* hB    = (short*)p; p += (size_t)32 * 8192 * 16 + 1024;  //  4.2 MB
    float* c0    = (float*)p; p += (size_t)32768 * 128 * 4;        // 16.8 MB
    float* c1    = (float*)p; p += (size_t)16384 * 128 * 4;        //  8.4 MB
    short* WcatC = (short*)p; p += (size_t)32 * 640 * 16;          // 320 KB

    // 1) leaf (includes WcatC reorder fold + on-the-fly W_leaf conversion)
    leaf_kernel<<<dim3(256, 2), 256, 0, stream>>>(
        x, W_leaf, W_l, W_r, b_leaf, hA, c0, WcatC);

    // 2..5) levels 1..8 as four fused pairs (ping-pong hA/c0 <-> hB/c1).
    //       grid = M1/64 = (2*M2)/64 blocks.
    fused2_kernel<<<256, 256, 0, stream>>>(hA, c0, WcatC, b, hB, c1, 8192); // L1,2
    fused2_kernel<<< 64, 256, 0, stream>>>(hB, c1, WcatC, b, hA, c0, 2048); // L3,4
    fused2_kernel<<< 16, 256, 0, stream>>>(hA, c0, WcatC, b, hB, c1,  512); // L5,6
    fused2_kernel<<<  4, 256, 0, stream>>>(hB, c1, WcatC, b, hA, c0,  128); // L7,8

    // 6) levels 9..12: single-block finisher (hA [32][64], c0 [128][128])
    finish_kernel<<<1, 512, 0, stream>>>(hA, c0, WcatC, b, out);
}

// Round 7
// 185.822 us; speedup vs baseline: 1.8123x; 1.8123x over previous
//
#include <hip/hip_runtime.h>
#include <hip/hip_bf16.h>
#include <math.h>

// TreeLSTM, B=8, L=4096, D=300, H=128, 12 levels. Round 13:
// - R10/R11/R12 post-mortem: every fused2 variant broke Wfr[5][8] register
//   residency (spill or remat traffic >> dispatch savings). LESSON: the
//   weight-stationary K-loop works ONLY in the level_ws shape -- one h-group
//   per block, Wfr loaded once at kernel scope, __launch_bounds__(256,2).
// - REVERT to R9 structure (best known good, 186.8us): leaf + 8x level_ws +
//   single-block finish (levels 9..12).
// - Banked improvement from R12 (correctness-proven there): reorder dispatch
//   folded into leaf blocks (y==0, x<160) and W_leaf staged fp32->bf16 on
//   the fly (WlfC buffer eliminated). 10 dispatches total.

typedef __attribute__((ext_vector_type(8))) short bfrag8;   // 8 bf16 = 4 VGPRs
typedef __attribute__((ext_vector_type(4))) float f32x4;

__device__ __forceinline__ float rcpf(float x) { return __builtin_amdgcn_rcpf(x); }
__device__ __forceinline__ float sigf(float x) { return rcpf(1.0f + __expf(-x)); }
__device__ __forceinline__ float tanh_f(float x) {
    float e = __expf(2.0f * x);              // x>>0: e=inf -> rcp=0 -> 1 ; x<<0: e=0 -> -1
    return 1.0f - 2.0f * rcpf(e + 1.0f);
}
__device__ __forceinline__ short f2bf(float f) {
    __hip_bfloat16 h = __float2bfloat16(f);
    return *reinterpret_cast<short*>(&h);
}
__device__ __forceinline__ bfrag8 pack8(f32x4 a, f32x4 b) {
    union { int i[4]; bfrag8 v; } u;
    asm("v_cvt_pk_bf16_f32 %0, %1, %2" : "=v"(u.i[0]) : "v"(a[0]), "v"(a[1]));
    asm("v_cvt_pk_bf16_f32 %0, %1, %2" : "=v"(u.i[1]) : "v"(a[2]), "v"(a[3]));
    asm("v_cvt_pk_bf16_f32 %0, %1, %2" : "=v"(u.i[2]) : "v"(b[0]), "v"(b[1]));
    asm("v_cvt_pk_bf16_f32 %0, %1, %2" : "=v"(u.i[3]) : "v"(b[2]), "v"(b[3]));
    return u.v;
}
#define GLDS(gp, lp) __builtin_amdgcn_global_load_lds( \
    (const __attribute__((address_space(1))) void*)(gp), \
    (__attribute__((address_space(3))) void*)(lp), 16, 0, 0)

// ---------------- leaf: [32768,320fp32]@[320,256] + bias, split h/c ----------------
// Fused x fp32->bf16 convert (swizzled GLDS source + cvt_pk), on-the-fly
// W_leaf fp32->bf16 B staging, and WcatC reorder folded into blocks
// (y==0, x<160) -- consumed only by later dispatches, no sync needed.
__global__ __launch_bounds__(256) void leaf_kernel(
    const float* __restrict__ x,     const float* __restrict__ Wleaf,
    const float* __restrict__ W_l,   const float* __restrict__ W_r,
    const float* __restrict__ bleaf,
    short* __restrict__ hD,       // level-1 A, chunk layout [32][16384] units
    float* __restrict__ cD,       // [32768][128] fp32
    short* __restrict__ Wcat_ch)  // [32][640] chunk units (for later levels)
{
    __shared__ float Als[128 * 64];     // 32 KB: [row][16 units of 4 floats], swizzled
    __shared__ short Bls[8 * 128 * 8];  // 16 KB: [c][n] units
    const int tid  = threadIdx.x;
    const int w    = tid >> 6, lane = tid & 63;
    const int quad = lane >> 4, l16 = lane & 15;
    const int mBlk = blockIdx.x * 128, nBlk = blockIdx.y * 128;
    const int waveM = (w >> 1) * 64, waveN = (w & 1) * 64;

    // ---- folded reorder: WcatC (163840 elems over 160 blocks x 1024) ----
    if (blockIdx.y == 0 && blockIdx.x < 160) {
        #pragma unroll
        for (int e = 0; e < 4; ++e) {
            int idx = blockIdx.x * 1024 + e * 256 + tid;
            int n = idx >> 8, k = idx & 255;
            float v = (k < 128) ? W_l[k * 640 + n] : W_r[(k - 128) * 640 + n];
            Wcat_ch[(((size_t)(k >> 3)) * 640 + n) * 8 + (k & 7)] = f2bf(v);
        }
    }

    f32x4 acc[4][4] = {};
    const f32x4 zero4 = {0.f, 0.f, 0.f, 0.f};

    for (int c = 0; c < 5; ++c) {           // K = 5 * 64 = 320 (300 + zero pad)
        const int k0c = c * 64;
        // ---- stage A (x) as fp32, XOR-swizzled source, linear LDS ----
        {
            const int q_lds = lane & 15;
            const int rsub  = lane >> 4;
            #pragma unroll
            for (int g = 0; g < 8; ++g) {
                int row = w * 32 + g * 4 + rsub;
                int q_g = (q_lds & 8) | ((q_lds & 7) ^ (row & 7));
                if (c < 4 || q_g < 11) {
                    GLDS(x + (size_t)(mBlk + row) * 300 + k0c + q_g * 4,
                         (char*)Als + (w * 32 + g * 4) * 256);
                } else {
                    *(f32x4*)((char*)Als + row * 256 + q_lds * 16) = zero4;  // pad k=300..319
                }
            }
        }
        // ---- stage B on the fly from W_leaf fp32 (1024 units, 4/thread) ----
        #pragma unroll
        for (int uu = 0; uu < 4; ++uu) {
            int id  = uu * 256 + tid;
            int ccl = id >> 7, nl = id & 127;   // chunk-in-iter [0,8), col [0,128)
            int k0  = (c * 8 + ccl) * 8;
            int n   = nBlk + nl;
            f32x4 v0, v1;
            #pragma unroll
            for (int jj = 0; jj < 4; ++jj)
                v0[jj] = (k0 + jj < 300) ? Wleaf[(size_t)(k0 + jj) * 256 + n] : 0.0f;
            #pragma unroll
            for (int jj = 0; jj < 4; ++jj)
                v1[jj] = (k0 + 4 + jj < 300) ? Wleaf[(size_t)(k0 + 4 + jj) * 256 + n] : 0.0f;
            *(bfrag8*)(Bls + (ccl * 128 + nl) * 8) = pack8(v0, v1);
        }
        __syncthreads();
        #pragma unroll
        for (int ks = 0; ks < 2; ++ks) {
            const int ca = ks * 4 + quad;
            bfrag8 af[4], bf4[4];
            #pragma unroll
            for (int i = 0; i < 4; ++i) {
                int r  = waveM + i * 16 + l16;
                int u0 = 2 * ca, u1 = 2 * ca + 1;
                int s0 = (u0 & 8) | ((u0 & 7) ^ (r & 7));
                int s1 = (u1 & 8) | ((u1 & 7) ^ (r & 7));
                f32x4 a0 = *(const f32x4*)(Als + r * 64 + s0 * 4);
                f32x4 a1 = *(const f32x4*)(Als + r * 64 + s1 * 4);
                af[i] = pack8(a0, a1);
            }
            #pragma unroll
            for (int jn = 0; jn < 4; ++jn)
                bf4[jn] = *(const bfrag8*)(Bls + (ca * 128 + waveN + jn * 16 + l16) * 8);
            #pragma unroll
            for (int i = 0; i < 4; ++i)
                #pragma unroll
                for (int jn = 0; jn < 4; ++jn)
                    acc[i][jn] = __builtin_amdgcn_mfma_f32_16x16x32_bf16(
                                     af[i], bf4[jn], acc[i][jn], 0, 0, 0);
        }
        __syncthreads();
    }

    #pragma unroll
    for (int i = 0; i < 4; ++i) {
        int row0 = mBlk + waveM + i * 16 + quad * 4;
        #pragma unroll
        for (int jn = 0; jn < 4; ++jn) {
            int col = nBlk + waveN + jn * 16 + l16;
            float bv = bleaf[col];
            #pragma unroll
            for (int rg = 0; rg < 4; ++rg) {
                float v = acc[i][jn][rg] + bv;
                int m = row0 + rg;
                if (nBlk == 0) {
                    int hc = col;
                    hD[(((size_t)((m & 1) * 16 + (hc >> 3))) * 16384 + (m >> 1)) * 8
                       + (hc & 7)] = f2bf(v);
                } else {
                    cD[(size_t)m * 128 + (col - 128)] = v;
                }
            }
        }
    }
}

// ---------------- weight-stationary level kernel (levels 1..8) ----------------
// PROVEN SHAPE -- do not wrap Wfr in a loop (R10/R11/R12 all spilled it).
__global__ __launch_bounds__(256, 2) void level_ws_kernel(
    const short* __restrict__ A,      // [32][M] chunk units
    const float* __restrict__ cprev,  // [2M][128] fp32
    const short* __restrict__ Wch,    // [32][640] chunk units
    const float* __restrict__ bias,   // [640]
    short* __restrict__ hout, float* __restrict__ cout_,
    int M)
{
    __shared__ short Als[32 * 64 * 8];   // 32 KB, [c][row]
    const int tid  = threadIdx.x;
    const int w    = tid >> 6, lane = tid & 63;
    const int quad = lane >> 4, l16 = lane & 15;
    const int j  = blockIdx.y;
    const int tb = blockIdx.x * 64;
    const int h  = j * 16 + l16;

    {
        int row = tb + lane; if (row >= M) row = 0;
        #pragma unroll
        for (int s = 0; s < 8; ++s)
            GLDS(A + ((size_t)(s * 4 + w) * M + row) * 8,
                 (char*)Als + (s * 4 + w) * 1024);
    }

    bfrag8 Wfr[5][8];
    #pragma unroll
    for (int g = 0; g < 5; ++g)
        #pragma unroll
        for (int s = 0; s < 8; ++s)
            Wfr[g][s] = *(const bfrag8*)(Wch + ((size_t)(s * 4 + quad) * 640
                                                + g * 128 + h) * 8);
    const float bi  = bias[h],       bfl = bias[128 + h], bfr_ = bias[256 + h];
    const float bo  = bias[384 + h], bg  = bias[512 + h];

    __syncthreads();

    f32x4 acc[5] = {};
    #pragma unroll
    for (int s = 0; s < 8; ++s) {
        bfrag8 af = *(const bfrag8*)(Als + ((s * 4 + quad) * 64 + w * 16 + l16) * 8);
        #pragma unroll
        for (int g = 0; g < 5; ++g)
            acc[g] = __builtin_amdgcn_mfma_f32_16x16x32_bf16(af, Wfr[g][s], acc[g], 0, 0, 0);
    }

    const int Mn = M >> 1;
    #pragma unroll
    for (int rg = 0; rg < 4; ++rg) {
        int m = tb + w * 16 + quad * 4 + rg;
        if (m < M) {
            float gi  = acc[0][rg] + bi;
            float gfl = acc[1][rg] + bfl;
            float gfr = acc[2][rg] + bfr_;
            float go  = acc[3][rg] + bo;
            float gg  = acc[4][rg] + bg;
            float cl  = cprev[(size_t)(2 * m) * 128 + h];
            float cr  = cprev[(size_t)(2 * m + 1) * 128 + h];
            float cn  = sigf(gfl) * cl + sigf(gfr) * cr + sigf(gi) * tanh_f(gg);
            float hn  = sigf(go) * tanh_f(cn);
            hout[(((size_t)((m & 1) * 16 + (h >> 3))) * Mn + (m >> 1)) * 8
                 + (h & 7)] = f2bf(hn);
            cout_[(size_t)m * 128 + h] = cn;
        }
    }
}

// ---------------- single-block finisher: levels 9..12 ----------------
__global__ __launch_bounds__(512) void finish_kernel(
    const short* __restrict__ hin,   // [32][64] units (128-row chunk layout)
    const float* __restrict__ cin,   // [128][128] f32
    const short* __restrict__ Wch, const float* __restrict__ bias,
    float* __restrict__ out)         // [8][128]
{
    __shared__ short hP[32 * 64 * 8];   // 32 KB ping
    __shared__ short hQ[32 * 32 * 8];   // 16 KB pong
    __shared__ float cA[128 * 128];     // 64 KB
    __shared__ float cB[64 * 128];      // 32 KB
    const int tid  = threadIdx.x;
    const int w    = tid >> 6, lane = tid & 63;
    const int quad = lane >> 4, l16 = lane & 15;
    const int h    = w * 16 + l16;      // wave = h-group

    #pragma unroll
    for (int g = 0; g < 4; ++g)
        GLDS(hin + ((size_t)((g * 8 + w) * 64 + lane)) * 8,
             (char*)hP + ((g * 8 + w) * 64) * 16);
    #pragma unroll
    for (int g = 0; g < 8; ++g)
        GLDS(cin + ((size_t)((g * 8 + w) * 64 + lane)) * 4,
             (char*)cA + ((g * 8 + w) * 64) * 16);

    bfrag8 Wfr[5][8];
    #pragma unroll
    for (int g = 0; g < 5; ++g)
        #pragma unroll
        for (int s = 0; s < 8; ++s)
            Wfr[g][s] = *(const bfrag8*)(Wch + ((size_t)(s * 4 + quad) * 640
                                                + g * 128 + h) * 8);
    const float bi  = bias[h],       bfl = bias[128 + h], bfr_ = bias[256 + h];
    const float bo  = bias[384 + h], bg  = bias[512 + h];

    __syncthreads();

    #pragma unroll
    for (int t = 0; t < 4; ++t) {              // levels 9..12
        const int Mo = 64 >> t;                // 64, 32, 16, 8
        const short* hsrc = (t & 1) ? hQ : hP;
        short* hdst       = (t & 1) ? hP : hQ;
        const float* cread  = (t & 1) ? cB : cA;
        float*       cwrite = (t & 1) ? cA : cB;
        const int nrt = (Mo + 15) >> 4;

        for (int rt = 0; rt < nrt; ++rt) {
            f32x4 acc[5] = {};
            #pragma unroll
            for (int s = 0; s < 8; ++s) {
                bfrag8 af = *(const bfrag8*)(hsrc + ((s * 4 + quad) * Mo
                                                     + rt * 16 + l16) * 8);
                #pragma unroll
                for (int g = 0; g < 5; ++g)
                    acc[g] = __builtin_amdgcn_mfma_f32_16x16x32_bf16(
                                 af, Wfr[g][s], acc[g], 0, 0, 0);
            }
            #pragma unroll
            for (int rg = 0; rg < 4; ++rg) {
                int m = rt * 16 + quad * 4 + rg;
                if (m < Mo) {
                    float gi  = acc[0][rg] + bi;
                    float gfl = acc[1][rg] + bfl;
                    float gfr = acc[2][rg] + bfr_;
                    float go  = acc[3][rg] + bo;
                    float gg  = acc[4][rg] + bg;
                    float cl  = cread[(2 * m) * 128 + h];
                    float cr  = cread[(2 * m + 1) * 128 + h];
                    float cn  = sigf(gfl) * cl + sigf(gfr) * cr + sigf(gi) * tanh_f(gg);
                    float hn  = sigf(go) * tanh_f(cn);
                    if (t == 3) {
                        out[(size_t)m * 128 + h] = hn;
                    } else {
                        hdst[(((m & 1) * 16 + (h >> 3)) * (Mo >> 1) + (m >> 1)) * 8
                             + (h & 7)] = f2bf(hn);
                        cwrite[m * 128 + h] = cn;
                    }
                }
            }
        }
        __syncthreads();
    }
}

extern "C" void kernel_launch(void* const* d_in, const int* in_sizes, int n_in,
                              void* d_out, int out_size, void* d_ws, size_t ws_size,
                              hipStream_t stream)
{
    const float* x      = (const float*)d_in[0];
    const float* W_leaf = (const float*)d_in[1];
    const float* b_leaf = (const float*)d_in[2];
    const float* W_l    = (const float*)d_in[3];
    const float* W_r    = (const float*)d_in[4];
    const float* b      = (const float*)d_in[5];
    float* out = (float*)d_out;

    // workspace (~38.2 MB)
    char* p = (char*)d_ws;
    short* hA    = (short*)p; p += (size_t)32 * 16384 * 16 + 1024; //  8.4 MB
    short* hB    = (short*)p; p += (size_t)32 * 8192 * 16 + 1024;  //  4.2 MB
    float* c0    = (float*)p; p += (size_t)32768 * 128 * 4;        // 16.8 MB
    float* c1    = (float*)p; p += (size_t)16384 * 128 * 4;        //  8.4 MB
    short* WcatC = (short*)p; p += (size_t)32 * 640 * 16;          // 320 KB

    // 1) leaf (includes WcatC reorder fold + on-the-fly W_leaf conversion)
    leaf_kernel<<<dim3(256, 2), 256, 0, stream>>>(
        x, W_leaf, W_l, W_r, b_leaf, hA, c0, WcatC);

    // 2..9) levels 1..8, proven per-level weight-stationary kernel
    const short* hin = hA; const float* cin = c0;
    int M = 16384;
    for (int lev = 1; lev <= 8; ++lev) {
        short* ho = (lev & 1) ? hB : hA;
        float* co = (lev & 1) ? c1 : c0;
        level_ws_kernel<<<dim3((M + 63) / 64, 8), 256, 0, stream>>>(
            hin, cin, WcatC, b, ho, co, M);
        hin = ho; cin = co;
        M >>= 1;
    }

    // 10) levels 9..12: single-block finisher (hA [32][64], c0 [128][128])
    finish_kernel<<<1, 512, 0, stream>>>(hA, c0, WcatC, b, out);
}

// Round 8
// 169.076 us; speedup vs baseline: 1.9918x; 1.0990x over previous
//
#include <hip/hip_runtime.h>
#include <hip/hip_bf16.h>
#include <math.h>

// TreeLSTM, B=8, L=4096, D=300, H=128, 12 levels. Round 14:
// - R13 post-mortem: dispatch-fold saved only ~1us -> per-dispatch cost is
//   ~2-4us, lever exhausted. New target: level_ws weight reload traffic.
//   Each block loads 160 KB of W from L2 (4 waves x 40 KB, same j-slice);
//   at 64 rows/block level 1 = 2048 blocks = 335 MB L2 traffic.
// - level_ws gains an nst row-subtile loop AROUND COMPUTE ONLY: Wfr is still
//   loaded ONCE at kernel scope (single load site -- R10/R12 broke residency
//   by loading it inside a loop; looping USES of a loop-invariant array is
//   fine, the s-loop already does). lev1 nst=4 (512 blocks, W traffic /4),
//   lev2 nst=2. Levels 3..8 nst=1 (keep block count for latency overlap).
// - leaf (reorder fold + on-the-fly W_leaf convert), finish: unchanged R13.

typedef __attribute__((ext_vector_type(8))) short bfrag8;   // 8 bf16 = 4 VGPRs
typedef __attribute__((ext_vector_type(4))) float f32x4;

__device__ __forceinline__ float rcpf(float x) { return __builtin_amdgcn_rcpf(x); }
__device__ __forceinline__ float sigf(float x) { return rcpf(1.0f + __expf(-x)); }
__device__ __forceinline__ float tanh_f(float x) {
    float e = __expf(2.0f * x);              // x>>0: e=inf -> rcp=0 -> 1 ; x<<0: e=0 -> -1
    return 1.0f - 2.0f * rcpf(e + 1.0f);
}
__device__ __forceinline__ short f2bf(float f) {
    __hip_bfloat16 h = __float2bfloat16(f);
    return *reinterpret_cast<short*>(&h);
}
__device__ __forceinline__ bfrag8 pack8(f32x4 a, f32x4 b) {
    union { int i[4]; bfrag8 v; } u;
    asm("v_cvt_pk_bf16_f32 %0, %1, %2" : "=v"(u.i[0]) : "v"(a[0]), "v"(a[1]));
    asm("v_cvt_pk_bf16_f32 %0, %1, %2" : "=v"(u.i[1]) : "v"(a[2]), "v"(a[3]));
    asm("v_cvt_pk_bf16_f32 %0, %1, %2" : "=v"(u.i[2]) : "v"(b[0]), "v"(b[1]));
    asm("v_cvt_pk_bf16_f32 %0, %1, %2" : "=v"(u.i[3]) : "v"(b[2]), "v"(b[3]));
    return u.v;
}
#define GLDS(gp, lp) __builtin_amdgcn_global_load_lds( \
    (const __attribute__((address_space(1))) void*)(gp), \
    (__attribute__((address_space(3))) void*)(lp), 16, 0, 0)

// ---------------- leaf: [32768,320fp32]@[320,256] + bias, split h/c ----------------
// Fused x fp32->bf16 convert (swizzled GLDS source + cvt_pk), on-the-fly
// W_leaf fp32->bf16 B staging, and WcatC reorder folded into blocks
// (y==0, x<160) -- consumed only by later dispatches, no sync needed.
__global__ __launch_bounds__(256) void leaf_kernel(
    const float* __restrict__ x,     const float* __restrict__ Wleaf,
    const float* __restrict__ W_l,   const float* __restrict__ W_r,
    const float* __restrict__ bleaf,
    short* __restrict__ hD,       // level-1 A, chunk layout [32][16384] units
    float* __restrict__ cD,       // [32768][128] fp32
    short* __restrict__ Wcat_ch)  // [32][640] chunk units (for later levels)
{
    __shared__ float Als[128 * 64];     // 32 KB: [row][16 units of 4 floats], swizzled
    __shared__ short Bls[8 * 128 * 8];  // 16 KB: [c][n] units
    const int tid  = threadIdx.x;
    const int w    = tid >> 6, lane = tid & 63;
    const int quad = lane >> 4, l16 = lane & 15;
    const int mBlk = blockIdx.x * 128, nBlk = blockIdx.y * 128;
    const int waveM = (w >> 1) * 64, waveN = (w & 1) * 64;

    // ---- folded reorder: WcatC (163840 elems over 160 blocks x 1024) ----
    if (blockIdx.y == 0 && blockIdx.x < 160) {
        #pragma unroll
        for (int e = 0; e < 4; ++e) {
            int idx = blockIdx.x * 1024 + e * 256 + tid;
            int n = idx >> 8, k = idx & 255;
            float v = (k < 128) ? W_l[k * 640 + n] : W_r[(k - 128) * 640 + n];
            Wcat_ch[(((size_t)(k >> 3)) * 640 + n) * 8 + (k & 7)] = f2bf(v);
        }
    }

    f32x4 acc[4][4] = {};
    const f32x4 zero4 = {0.f, 0.f, 0.f, 0.f};

    for (int c = 0; c < 5; ++c) {           // K = 5 * 64 = 320 (300 + zero pad)
        const int k0c = c * 64;
        // ---- stage A (x) as fp32, XOR-swizzled source, linear LDS ----
        {
            const int q_lds = lane & 15;
            const int rsub  = lane >> 4;
            #pragma unroll
            for (int g = 0; g < 8; ++g) {
                int row = w * 32 + g * 4 + rsub;
                int q_g = (q_lds & 8) | ((q_lds & 7) ^ (row & 7));
                if (c < 4 || q_g < 11) {
                    GLDS(x + (size_t)(mBlk + row) * 300 + k0c + q_g * 4,
                         (char*)Als + (w * 32 + g * 4) * 256);
                } else {
                    *(f32x4*)((char*)Als + row * 256 + q_lds * 16) = zero4;  // pad k=300..319
                }
            }
        }
        // ---- stage B on the fly from W_leaf fp32 (1024 units, 4/thread) ----
        #pragma unroll
        for (int uu = 0; uu < 4; ++uu) {
            int id  = uu * 256 + tid;
            int ccl = id >> 7, nl = id & 127;   // chunk-in-iter [0,8), col [0,128)
            int k0  = (c * 8 + ccl) * 8;
            int n   = nBlk + nl;
            f32x4 v0, v1;
            #pragma unroll
            for (int jj = 0; jj < 4; ++jj)
                v0[jj] = (k0 + jj < 300) ? Wleaf[(size_t)(k0 + jj) * 256 + n] : 0.0f;
            #pragma unroll
            for (int jj = 0; jj < 4; ++jj)
                v1[jj] = (k0 + 4 + jj < 300) ? Wleaf[(size_t)(k0 + 4 + jj) * 256 + n] : 0.0f;
            *(bfrag8*)(Bls + (ccl * 128 + nl) * 8) = pack8(v0, v1);
        }
        __syncthreads();
        #pragma unroll
        for (int ks = 0; ks < 2; ++ks) {
            const int ca = ks * 4 + quad;
            bfrag8 af[4], bf4[4];
            #pragma unroll
            for (int i = 0; i < 4; ++i) {
                int r  = waveM + i * 16 + l16;
                int u0 = 2 * ca, u1 = 2 * ca + 1;
                int s0 = (u0 & 8) | ((u0 & 7) ^ (r & 7));
                int s1 = (u1 & 8) | ((u1 & 7) ^ (r & 7));
                f32x4 a0 = *(const f32x4*)(Als + r * 64 + s0 * 4);
                f32x4 a1 = *(const f32x4*)(Als + r * 64 + s1 * 4);
                af[i] = pack8(a0, a1);
            }
            #pragma unroll
            for (int jn = 0; jn < 4; ++jn)
                bf4[jn] = *(const bfrag8*)(Bls + (ca * 128 + waveN + jn * 16 + l16) * 8);
            #pragma unroll
            for (int i = 0; i < 4; ++i)
                #pragma unroll
                for (int jn = 0; jn < 4; ++jn)
                    acc[i][jn] = __builtin_amdgcn_mfma_f32_16x16x32_bf16(
                                     af[i], bf4[jn], acc[i][jn], 0, 0, 0);
        }
        __syncthreads();
    }

    #pragma unroll
    for (int i = 0; i < 4; ++i) {
        int row0 = mBlk + waveM + i * 16 + quad * 4;
        #pragma unroll
        for (int jn = 0; jn < 4; ++jn) {
            int col = nBlk + waveN + jn * 16 + l16;
            float bv = bleaf[col];
            #pragma unroll
            for (int rg = 0; rg < 4; ++rg) {
                float v = acc[i][jn][rg] + bv;
                int m = row0 + rg;
                if (nBlk == 0) {
                    int hc = col;
                    hD[(((size_t)((m & 1) * 16 + (hc >> 3))) * 16384 + (m >> 1)) * 8
                       + (hc & 7)] = f2bf(v);
                } else {
                    cD[(size_t)m * 128 + (col - 128)] = v;
                }
            }
        }
    }
}

// ---------------- weight-stationary level kernel (levels 1..8) ----------------
// PROVEN SHAPE: Wfr loaded ONCE at kernel scope (single load site). nst
// row-subtiles per block amortize that load (compute loop only).
__global__ __launch_bounds__(256, 2) void level_ws_kernel(
    const short* __restrict__ A,      // [32][M] chunk units
    const float* __restrict__ cprev,  // [2M][128] fp32
    const short* __restrict__ Wch,    // [32][640] chunk units
    const float* __restrict__ bias,   // [640]
    short* __restrict__ hout, float* __restrict__ cout_,
    int M, int nst)
{
    __shared__ short Als[32 * 64 * 8];   // 32 KB, [c][row]
    const int tid  = threadIdx.x;
    const int w    = tid >> 6, lane = tid & 63;
    const int quad = lane >> 4, l16 = lane & 15;
    const int j   = blockIdx.y;
    const int tb0 = blockIdx.x * 64 * nst;
    const int h   = j * 16 + l16;

    // stage subtile 0 (overlaps the Wfr loads below)
    #pragma unroll
    for (int s = 0; s < 8; ++s)
        GLDS(A + ((size_t)(s * 4 + w) * M + tb0 + lane) * 8,
             (char*)Als + (s * 4 + w) * 1024);

    bfrag8 Wfr[5][8];
    #pragma unroll
    for (int g = 0; g < 5; ++g)
        #pragma unroll
        for (int s = 0; s < 8; ++s)
            Wfr[g][s] = *(const bfrag8*)(Wch + ((size_t)(s * 4 + quad) * 640
                                                + g * 128 + h) * 8);
    const float bi  = bias[h],       bfl = bias[128 + h], bfr_ = bias[256 + h];
    const float bo  = bias[384 + h], bg  = bias[512 + h];

    const int Mn = M >> 1;
    for (int st = 0; st < nst; ++st) {
        const int tb = tb0 + st * 64;
        __syncthreads();                 // staging of subtile st complete

        f32x4 acc[5] = {};
        #pragma unroll
        for (int s = 0; s < 8; ++s) {
            bfrag8 af = *(const bfrag8*)(Als + ((s * 4 + quad) * 64 + w * 16 + l16) * 8);
            #pragma unroll
            for (int g = 0; g < 5; ++g)
                acc[g] = __builtin_amdgcn_mfma_f32_16x16x32_bf16(af, Wfr[g][s], acc[g], 0, 0, 0);
        }

        if (st + 1 < nst) {
            __syncthreads();             // all Als reads done; restage
            #pragma unroll
            for (int s = 0; s < 8; ++s)
                GLDS(A + ((size_t)(s * 4 + w) * M + tb + 64 + lane) * 8,
                     (char*)Als + (s * 4 + w) * 1024);
        }

        #pragma unroll
        for (int rg = 0; rg < 4; ++rg) {
            int m = tb + w * 16 + quad * 4 + rg;
            float gi  = acc[0][rg] + bi;
            float gfl = acc[1][rg] + bfl;
            float gfr = acc[2][rg] + bfr_;
            float go  = acc[3][rg] + bo;
            float gg  = acc[4][rg] + bg;
            float cl  = cprev[(size_t)(2 * m) * 128 + h];
            float cr  = cprev[(size_t)(2 * m + 1) * 128 + h];
            float cn  = sigf(gfl) * cl + sigf(gfr) * cr + sigf(gi) * tanh_f(gg);
            float hn  = sigf(go) * tanh_f(cn);
            hout[(((size_t)((m & 1) * 16 + (h >> 3))) * Mn + (m >> 1)) * 8
                 + (h & 7)] = f2bf(hn);
            cout_[(size_t)m * 128 + h] = cn;
        }
    }
}

// ---------------- single-block finisher: levels 9..12 ----------------
__global__ __launch_bounds__(512) void finish_kernel(
    const short* __restrict__ hin,   // [32][64] units (128-row chunk layout)
    const float* __restrict__ cin,   // [128][128] f32
    const short* __restrict__ Wch, const float* __restrict__ bias,
    float* __restrict__ out)         // [8][128]
{
    __shared__ short hP[32 * 64 * 8];   // 32 KB ping
    __shared__ short hQ[32 * 32 * 8];   // 16 KB pong
    __shared__ float cA[128 * 128];     // 64 KB
    __shared__ float cB[64 * 128];      // 32 KB
    const int tid  = threadIdx.x;
    const int w    = tid >> 6, lane = tid & 63;
    const int quad = lane >> 4, l16 = lane & 15;
    const int h    = w * 16 + l16;      // wave = h-group

    #pragma unroll
    for (int g = 0; g < 4; ++g)
        GLDS(hin + ((size_t)((g * 8 + w) * 64 + lane)) * 8,
             (char*)hP + ((g * 8 + w) * 64) * 16);
    #pragma unroll
    for (int g = 0; g < 8; ++g)
        GLDS(cin + ((size_t)((g * 8 + w) * 64 + lane)) * 4,
             (char*)cA + ((g * 8 + w) * 64) * 16);

    bfrag8 Wfr[5][8];
    #pragma unroll
    for (int g = 0; g < 5; ++g)
        #pragma unroll
        for (int s = 0; s < 8; ++s)
            Wfr[g][s] = *(const bfrag8*)(Wch + ((size_t)(s * 4 + quad) * 640
                                                + g * 128 + h) * 8);
    const float bi  = bias[h],       bfl = bias[128 + h], bfr_ = bias[256 + h];
    const float bo  = bias[384 + h], bg  = bias[512 + h];

    __syncthreads();

    #pragma unroll
    for (int t = 0; t < 4; ++t) {              // levels 9..12
        const int Mo = 64 >> t;                // 64, 32, 16, 8
        const short* hsrc = (t & 1) ? hQ : hP;
        short* hdst       = (t & 1) ? hP : hQ;
        const float* cread  = (t & 1) ? cB : cA;
        float*       cwrite = (t & 1) ? cA : cB;
        const int nrt = (Mo + 15) >> 4;

        for (int rt = 0; rt < nrt; ++rt) {
            f32x4 acc[5] = {};
            #pragma unroll
            for (int s = 0; s < 8; ++s) {
                bfrag8 af = *(const bfrag8*)(hsrc + ((s * 4 + quad) * Mo
                                                     + rt * 16 + l16) * 8);
                #pragma unroll
                for (int g = 0; g < 5; ++g)
                    acc[g] = __builtin_amdgcn_mfma_f32_16x16x32_bf16(
                                 af, Wfr[g][s], acc[g], 0, 0, 0);
            }
            #pragma unroll
            for (int rg = 0; rg < 4; ++rg) {
                int m = rt * 16 + quad * 4 + rg;
                if (m < Mo) {
                    float gi  = acc[0][rg] + bi;
                    float gfl = acc[1][rg] + bfl;
                    float gfr = acc[2][rg] + bfr_;
                    float go  = acc[3][rg] + bo;
                    float gg  = acc[4][rg] + bg;
                    float cl  = cread[(2 * m) * 128 + h];
                    float cr  = cread[(2 * m + 1) * 128 + h];
                    float cn  = sigf(gfl) * cl + sigf(gfr) * cr + sigf(gi) * tanh_f(gg);
                    float hn  = sigf(go) * tanh_f(cn);
                    if (t == 3) {
                        out[(size_t)m * 128 + h] = hn;
                    } else {
                        hdst[(((m & 1) * 16 + (h >> 3)) * (Mo >> 1) + (m >> 1)) * 8
                             + (h & 7)] = f2bf(hn);
                        cwrite[m * 128 + h] = cn;
                    }
                }
            }
        }
        __syncthreads();
    }
}

extern "C" void kernel_launch(void* const* d_in, const int* in_sizes, int n_in,
                              void* d_out, int out_size, void* d_ws, size_t ws_size,
                              hipStream_t stream)
{
    const float* x      = (const float*)d_in[0];
    const float* W_leaf = (const float*)d_in[1];
    const float* b_leaf = (const float*)d_in[2];
    const float* W_l    = (const float*)d_in[3];
    const float* W_r    = (const float*)d_in[4];
    const float* b      = (const float*)d_in[5];
    float* out = (float*)d_out;

    // workspace (~38.2 MB)
    char* p = (char*)d_ws;
    short* hA    = (short*)p; p += (size_t)32 * 16384 * 16 + 1024; //  8.4 MB
    short* hB    = (short*)p; p += (size_t)32 * 8192 * 16 + 1024;  //  4.2 MB
    float* c0    = (float*)p; p += (size_t)32768 * 128 * 4;        // 16.8 MB
    float* c1    = (float*)p; p += (size_t)16384 * 128 * 4;        //  8.4 MB
    short* WcatC = (short*)p; p += (size_t)32 * 640 * 16;          // 320 KB

    // 1) leaf (includes WcatC reorder fold + on-the-fly W_leaf conversion)
    leaf_kernel<<<dim3(256, 2), 256, 0, stream>>>(
        x, W_leaf, W_l, W_r, b_leaf, hA, c0, WcatC);

    // 2..9) levels 1..8, weight-stationary; nst amortizes Wfr load on the
    //       two big levels (keeps >=2 blocks/CU everywhere).
    const short* hin = hA; const float* cin = c0;
    int M = 16384;
    for (int lev = 1; lev <= 8; ++lev) {
        short* ho = (lev & 1) ? hB : hA;
        float* co = (lev & 1) ? c1 : c0;
        int nst = (lev == 1) ? 4 : (lev == 2) ? 2 : 1;
        level_ws_kernel<<<dim3(M / (64 * nst), 8), 256, 0, stream>>>(
            hin, cin, WcatC, b, ho, co, M, nst);
        hin = ho; cin = co;
        M >>= 1;
    }

    // 10) levels 9..12: single-block finisher (hA [32][64], c0 [128][128])
    finish_kernel<<<1, 512, 0, stream>>>(hA, c0, WcatC, b, out);
}